// Round 5
// baseline (170.250 us; speedup 1.0000x reference)
//
#include <hip/hip_runtime.h>

// EncoderDecoderLSTM fused kernel for MI355X (gfx950).
//
// Math: state never updates, h0=c0=0  =>
//   gates = input @ (W_ih @ enc_W)^T + (W_ih @ enc_b + b_ih + b_hh)
//   f-gate dead (multiplies c0=0). Only i,g,o needed (768 of 1024 rows).
//   h = sigmoid(o) * tanh( sigmoid(i) * tanh(g) ),  out = h @ dec_W^T + dec_b
//
// R5: R2 skeleton (best so far: 89us, VALUBusy 70) + division/trans-free
// packed-f16 activation with THREE INDEPENDENT gate chains (ILP):
//   sigma(x) = 0.5(1+tanh(x/2)); tanh(4u) via Pade[7/6] on clamped u;
//   reciprocal via f16 magic (0x7800-bits, valid for den in [1,13.9]) +
//   2 packed Newton steps. Pre-scales (i,o:/8; g:/4) folded into weights.

typedef _Float16 f16x8 __attribute__((ext_vector_type(8)));
typedef _Float16 f16x4 __attribute__((ext_vector_type(4)));
typedef float    f32x4 __attribute__((ext_vector_type(4)));
typedef _Float16 hx2   __attribute__((ext_vector_type(2)));
typedef __fp16   pk16x2 __attribute__((ext_vector_type(2)));

#define T_IN 2048
#define TT   2112   // T + future_n
#define FIN  32
#define FOUT 32

// ws layout (bytes): Mb @0 (49152), fb @49152 (3072), decWb @52224 (16384)
#define WS_FB_OFF   49152
#define WS_DECW_OFF 52224

union PkCast { pk16x2 p; hx2 h; unsigned u; };

__device__ __forceinline__ hx2 pk2(float a, float b) {
    PkCast c; c.p = __builtin_amdgcn_cvt_pkrtz(a, b); return c.h;
}
__device__ __forceinline__ hx2 splat(float v) {
    _Float16 h = (_Float16)v; return (hx2){h, h};
}
// packed-f16 reciprocal for d in [1, 14): magic seed (err<13%) + 2 Newton
// (err -> ~2e-4 rel + f16 roundoff). Single v_sub_u32 seeds BOTH halves
// (no borrow: per-half bits in [0x3C00,0x4AE7], result in [0x2D19,0x3C00]).
__device__ __forceinline__ hx2 pk_rcp(hx2 d, hx2 TWO) {
    union { hx2 h; unsigned u; } a, r;
    a.h = d;
    r.u = 0x78007800u - a.u;
    hx2 y = r.h;
    y = y * (TWO - d * y);
    y = y * (TWO - d * y);
    return y;
}

__global__ __launch_bounds__(256) void prep2(
    const float* __restrict__ enc_W, const float* __restrict__ enc_b,
    const float* __restrict__ W_ih, const float* __restrict__ b_ih,
    const float* __restrict__ b_hh, const float* __restrict__ dec_W,
    _Float16* __restrict__ Mb, float* __restrict__ fb, _Float16* __restrict__ decWb) {
    const int blk = blockIdx.x;
    const int tid = threadIdx.x;
    if (blk < 768) {
        // row gg: 0-255 = i (sg=gg), 256-511 = g (sg=gg+256), 512-767 = o
        const int gg = blk, sg = gg + (gg >= 256 ? 256 : 0);
        // pre-scale for Pade arg u: i,o -> x/2/4 = /8; g -> x/4
        const float scale = (gg >= 256 && gg < 512) ? 0.25f : 0.125f;
        const float* wr = W_ih + (size_t)sg * 256;
        const int f = tid & 31, r8 = tid >> 5;
        float acc = 0.f;
#pragma unroll
        for (int k = 0; k < 32; ++k) {
            int r = r8 * 32 + k;
            acc = fmaf(wr[r], enc_W[r * 32 + f], acc);
        }
        __shared__ float red[256];
        __shared__ float redb[256];
        __shared__ float red2[32];
        red[tid]  = acc;
        redb[tid] = wr[tid] * enc_b[tid];
        __syncthreads();
        if (tid < 32) {
            float s = 0.f;
#pragma unroll
            for (int k = 0; k < 8; ++k) s += red[k * 32 + tid];
            Mb[gg * 32 + tid] = (_Float16)(s * scale);
        } else if (tid >= 128 && tid < 160) {
            int t2 = tid - 128;
            float s2 = 0.f;
#pragma unroll
            for (int k = 0; k < 8; ++k) s2 += redb[t2 * 8 + k];
            red2[t2] = s2;
        }
        __syncthreads();
        if (tid == 0) {
            float t = b_ih[sg] + b_hh[sg];
#pragma unroll
            for (int k = 0; k < 32; ++k) t += red2[k];
            fb[gg] = t * scale;
        }
    } else {
        // blocks 768..775: dec_W f32 -> f16 (8192 elems, 4/thread)
        int i = (blk - 768) * 1024 + tid * 4;
        f32x4 v = *(const f32x4*)(dec_W + i);
        f16x4 o;
#pragma unroll
        for (int j = 0; j < 4; ++j) o[j] = (_Float16)v[j];
        *(f16x4*)(decWb + i) = o;
    }
}

__global__ __launch_bounds__(256) void lstm_main(
    const float* __restrict__ in, const _Float16* __restrict__ Mb,
    const float* __restrict__ fb, const _Float16* __restrict__ decWb,
    const float* __restrict__ dec_b, float* __restrict__ out) {
    // per-wave LDS: h tile [2 s][16 t][40 f16] (pitch 40: 2-way alias = free)
    __shared__ _Float16 hbuf[4][2][16 * 40];

    const int lane = threadIdx.x & 63;
    const int w    = threadIdx.x >> 6;
    const int l16  = lane & 15;
    const int q    = lane >> 4;
    const int wave = blockIdx.x * 4 + w;
    const int rowbase = wave * 32;            // 2112 % 32 == 0: one b per wave
    const int b  = rowbase / TT;
    const int t0 = rowbase - b * TT;

    // Pade[7/6] tanh(4u), u clamped to [-1,1], w = u^2 (verified: exact at
    // tanh(1), tanh(2); err 2e-4 at tanh(4)):
    const hx2 C0 = splat(4.0f),      C1 = splat(7.757576f), C2 = splat(2.068687f);
    const hx2 D1 = splat(7.272727f), D2 = splat(5.171717f), D3 = splat(0.394036f);
    const hx2 ONE = splat(1.0f), H05 = splat(0.5f), TWO = splat(2.0f);
    // tanh(c)/c for z=c^2 in [0,1]: cubic fit, err ~1e-4..5e-4
    const hx2 T0 = splat(0.99980f), T1 = splat(-0.32806f),
              T2 = splat(0.11306f), T3 = splat(-0.02344f);

    // Input B-fragments: B[k=q*8+j][n=l16] = input[b][min(t,2047)][q*8+j]
    f16x8 bfr[2];
#pragma unroll
    for (int s = 0; s < 2; ++s) {
        int t  = t0 + s * 16 + l16;
        int tr = t < T_IN ? t : (T_IN - 1);
        const float* p = in + ((size_t)(b * T_IN + tr)) * FIN + q * 8;
        f32x4 u0 = *(const f32x4*)(p);
        f32x4 u1 = *(const f32x4*)(p + 4);
        union { hx2 h[4]; f16x8 v; } pk;
        pk.h[0] = pk2(u0[0], u0[1]); pk.h[1] = pk2(u0[2], u0[3]);
        pk.h[2] = pk2(u1[0], u1[1]); pk.h[3] = pk2(u1[2], u1[3]);
        bfr[s] = pk.v;
    }

    // decoder acc starts at dec_b (rides the MFMA C operand)
    f32x4 dacc[2][2];
#pragma unroll
    for (int ot = 0; ot < 2; ++ot) {
        f32x4 db = *(const f32x4*)(dec_b + ot * 16 + q * 4);
        dacc[0][ot] = db; dacc[1][ot] = db;
    }

    for (int hc = 0; hc < 8; ++hc) {
        const int hb = hc * 32;
        // Gate weight A-frags + bias C-frags
        f16x8 afr[3][2];
        f32x4 fbv[3][2];
#pragma unroll
        for (int gt = 0; gt < 3; ++gt)
#pragma unroll
            for (int X = 0; X < 2; ++X) {
                int grow = gt * 256 + hb + X * 16;
                afr[gt][X] = *(const f16x8*)(Mb + (size_t)(grow + l16) * 32 + q * 8);
                fbv[gt][X] = *(const f32x4*)(fb + grow + q * 4);
            }
        // Decoder A-frags: A2[m=ot*16+l16][k -> hid=hb+q*8+j]
        f16x8 a2[2];
#pragma unroll
        for (int ot = 0; ot < 2; ++ot)
            a2[ot] = *(const f16x8*)(decWb + (size_t)(ot * 16 + l16) * 256 + hb + q * 8);

#pragma unroll
        for (int s = 0; s < 2; ++s) {
            // D[m = gate hid][n = t]; pre-scaled bias rides the C operand.
            // Gate values arrive pre-scaled: i/8, g/4, o/8 == Pade u args.
            f32x4 gi[2], gg[2], go[2];
#pragma unroll
            for (int X = 0; X < 2; ++X) {
                gi[X] = __builtin_amdgcn_mfma_f32_16x16x32_f16(afr[0][X], bfr[s], fbv[0][X], 0, 0, 0);
                gg[X] = __builtin_amdgcn_mfma_f32_16x16x32_f16(afr[1][X], bfr[s], fbv[1][X], 0, 0, 0);
                go[X] = __builtin_amdgcn_mfma_f32_16x16x32_f16(afr[2][X], bfr[s], fbv[2][X], 0, 0, 0);
            }
            _Float16* hp = &hbuf[w][s][0];
#pragma unroll
            for (int X = 0; X < 2; ++X) {
                hx2 hpair[2];
#pragma unroll
                for (int p = 0; p < 2; ++p) {
                    // clamp in f32 (guaranteed single v_med3), then pack
                    hx2 ui = pk2(__builtin_amdgcn_fmed3f(gi[X][2*p],   -1.f, 1.f),
                                 __builtin_amdgcn_fmed3f(gi[X][2*p+1], -1.f, 1.f));
                    hx2 ug = pk2(__builtin_amdgcn_fmed3f(gg[X][2*p],   -1.f, 1.f),
                                 __builtin_amdgcn_fmed3f(gg[X][2*p+1], -1.f, 1.f));
                    hx2 uo = pk2(__builtin_amdgcn_fmed3f(go[X][2*p],   -1.f, 1.f),
                                 __builtin_amdgcn_fmed3f(go[X][2*p+1], -1.f, 1.f));
                    // three INDEPENDENT packed rational-tanh chains (ILP)
                    hx2 wi = ui * ui, wg = ug * ug, wo = uo * uo;
                    hx2 ni = ui * (wi * (wi * C2 + C1) + C0);
                    hx2 ng = ug * (wg * (wg * C2 + C1) + C0);
                    hx2 no = uo * (wo * (wo * C2 + C1) + C0);
                    hx2 di = wi * (wi * (wi * D3 + D2) + D1) + ONE;
                    hx2 dg = wg * (wg * (wg * D3 + D2) + D1) + ONE;
                    hx2 dd = wo * (wo * (wo * D3 + D2) + D1) + ONE;
                    hx2 ti = ni * pk_rcp(di, TWO);   // tanh(i/2)
                    hx2 tg = ng * pk_rcp(dg, TWO);   // tanh(g)
                    hx2 to = no * pk_rcp(dd, TWO);   // tanh(o/2)
                    hx2 si = ti * H05 + H05;         // sigmoid(i)
                    hx2 so = to * H05 + H05;         // sigmoid(o)
                    hx2 c  = si * tg;
                    hx2 z  = c * c;
                    hx2 P  = z * (z * (z * T3 + T2) + T1) + T0;
                    hpair[p] = so * (c * P);         // h = sigmoid(o)*tanh(c)
                }
                // h already packed f16: one 8B LDS write per X
                union { hx2 h[2]; uint2 u; } hw;
                hw.h[0] = hpair[0]; hw.h[1] = hpair[1];
                *(uint2*)(hp + l16 * 40 + X * 16 + q * 4) = hw.u;
            }
            // wave-internal cross-lane LDS handoff
            asm volatile("s_waitcnt lgkmcnt(0)" ::: "memory");
            // B2[k=q*8+j][n=l16] = h[t=l16][hb + q*8+j]
            f16x8 b2 = *(const f16x8*)(hp + l16 * 40 + q * 8);
#pragma unroll
            for (int ot = 0; ot < 2; ++ot)
                dacc[s][ot] = __builtin_amdgcn_mfma_f32_16x16x32_f16(a2[ot], b2, dacc[s][ot], 0, 0, 0);
        }
    }

    // D2[od = ot*16 + 4q + r][t=l16] -> out[(b*TT+t)*32 + od], float4 per lane
#pragma unroll
    for (int s = 0; s < 2; ++s) {
        int t = t0 + s * 16 + l16;
        size_t ro = ((size_t)(b * TT + t)) * FOUT;
#pragma unroll
        for (int ot = 0; ot < 2; ++ot)
            *(f32x4*)(out + ro + ot * 16 + q * 4) = dacc[s][ot];
    }
}

extern "C" void kernel_launch(void* const* d_in, const int* in_sizes, int n_in,
                              void* d_out, int out_size, void* d_ws, size_t ws_size,
                              hipStream_t stream) {
    const float* input = (const float*)d_in[0];
    const float* enc_W = (const float*)d_in[1];
    const float* enc_b = (const float*)d_in[2];
    const float* W_ih  = (const float*)d_in[3];
    // d_in[4] = W_hh: unused (h0 = 0 -> state_gates = b_hh only)
    const float* b_ih  = (const float*)d_in[5];
    const float* b_hh  = (const float*)d_in[6];
    const float* dec_W = (const float*)d_in[7];
    const float* dec_b = (const float*)d_in[8];
    // d_in[9] = future_n (fixed 64, baked into TT)

    _Float16* Mb    = (_Float16*)d_ws;
    float*    fb    = (float*)((char*)d_ws + WS_FB_OFF);
    _Float16* decWb = (_Float16*)((char*)d_ws + WS_DECW_OFF);
    float*    out   = (float*)d_out;

    prep2<<<776, 256, 0, stream>>>(enc_W, enc_b, W_ih, b_ih, b_hh, dec_W, Mb, fb, decWb);
    // 128 b * 2112 t rows / 32 rows-per-wave = 8448 waves; 4 waves/block
    lstm_main<<<2112, 256, 0, stream>>>(input, Mb, fb, decWb, dec_b, out);
}